// Round 1
// 2355.234 us; speedup vs baseline: 1.2302x; 1.2302x over previous
//
#include <hip/hip_runtime.h>

#define NB 8
#define NPTS 16384
#define S 1024
#define KNEI 32
#define MROWS (NB*S*KNEI)   // 262144

// Dynamic LDS for fps: x[16384] + 2*16 val slots + 2*16 idx slots.
#define FPS_LDS_BYTES (NPTS*4 + 2*16*4 + 2*16*4)   // 65792 B

// Value-only max combine via DPP (VALU pipe): pull value from another lane
// per CTRL, identity -1.0f for invalid lanes (all dists >= 0).
#define DPP_MAXF(CTRL, v) do {                                                \
    int _o = __builtin_amdgcn_update_dpp((int)0xBF800000, __float_as_int(v),  \
                                         (CTRL), 0xF, 0xF, false);            \
    float _f = __int_as_float(_o);                                            \
    (v) = fmaxf((v), _f);                                                     \
  } while (0)

#define DPP_ROW_SHR1   0x111
#define DPP_ROW_SHR2   0x112
#define DPP_ROW_SHR4   0x114
#define DPP_ROW_SHR8   0x118
#define DPP_ROW_BCAST15 0x142
#define DPP_ROW_BCAST31 0x143

// ---------------------------------------------------------------------------
// FPS r10: r9 was VALU-issue-bound (~520 wave-instrs/step; VALUBusy ~80% of
// the 8-active-CU ceiling). Remove the LDS x/dist round-trips entirely:
// dist[16] + x/y/z[16] live in registers (64 VGPRs, 4 waves/SIMD still OK).
// Argmax is restructured: per-point only a running value-max (1 v_max), a
// value-only DPP wave reduce (2 instr/stage vs 9 for pair combine), then the
// index is located AFTER the block max bm is known: 16-wide exact-equality
// scan (bm is bit-copied from some lane's dist, all values are canonical
// non-negative floats -> bitwise == numeric equality) + ballot/ctz.
// Contiguous ownership (thread t owns points [16t,16t+16)) makes global
// index order monotone in (wave, lane, j), so smallest-index-on-tie =
// lowest ballot bit / lowest slot. Exact-match discipline unchanged:
// no fp contraction, ((dx^2+dy^2)+dz^2) order, first-occurrence argmax.
// LDS keeps only the x-plane (centroid broadcast) + 2x16 reduce slots.
// ---------------------------------------------------------------------------
__global__ __launch_bounds__(1024) void fps_kernel(const float* __restrict__ pos,
                                                   float* __restrict__ centers){
#pragma clang fp contract(off)
  extern __shared__ float smem[];
  float* sx  = smem;                          // [NPTS]
  float* swv = smem + NPTS;                   // [2][16]
  int*   swi = (int*)(smem + NPTS + 32);      // [2][16]
  const int b = blockIdx.x;
  const int t = threadIdx.x;
  const int wid = t >> 6, lane = t & 63;
  const float* pb = pos + (size_t)b * NPTS * 3;

  float px[16], py[16], pz[16], dist[16];
  {
    const float4* src = (const float4*)(pb + t*48);   // 16 pts * 3 = 48 floats
#pragma unroll
    for (int g = 0; g < 4; ++g){
      float4 a = src[g*3+0], q = src[g*3+1], c = src[g*3+2];
      px[g*4+0]=a.x;  py[g*4+0]=a.y;  pz[g*4+0]=a.z;
      px[g*4+1]=a.w;  py[g*4+1]=q.x;  pz[g*4+1]=q.y;
      px[g*4+2]=q.z;  py[g*4+2]=q.w;  pz[g*4+2]=c.x;
      px[g*4+3]=c.y;  py[g*4+3]=c.z;  pz[g*4+3]=c.w;
    }
  }
#pragma unroll
  for (int j = 0; j < 16; ++j){
    asm volatile("" : "+v"(px[j]), "+v"(py[j]), "+v"(pz[j]));  // no remat
    dist[j] = 1e10f;
  }
  // stage x plane for centroid-x broadcast reads
#pragma unroll
  for (int g = 0; g < 4; ++g){
    *(float4*)&sx[t*16 + g*4] =
        make_float4(px[g*4+0], px[g*4+1], px[g*4+2], px[g*4+3]);
  }
  float cx = pb[0], cy = pb[1], cz = pb[2];    // far=0 initial centroid
  __syncthreads();

  for (int s = 0; s < S; ++s){
    if (t == 0){
      float* cd = centers + (size_t)(b*S + s)*3;
      cd[0] = cx; cd[1] = cy; cd[2] = cz;
    }
    float bv = -1.0f;
#pragma unroll
    for (int j = 0; j < 16; ++j){
      float dx = px[j]-cx, dy = py[j]-cy, dz = pz[j]-cz;
      float t1 = dx*dx, t2 = dy*dy, t3 = dz*dz;
      float d = (t1 + t2) + t3;
      float old = dist[j];
      float nd = old < d ? old : d;            // jnp.minimum
      dist[j] = nd;
      bv = fmaxf(bv, nd);
    }
    // wave-level value max (DPP, VALU pipe)
    DPP_MAXF(DPP_ROW_SHR1,   bv);
    DPP_MAXF(DPP_ROW_SHR2,   bv);
    DPP_MAXF(DPP_ROW_SHR4,   bv);
    DPP_MAXF(DPP_ROW_SHR8,   bv);    // lane 15 of each row = row max
    DPP_MAXF(DPP_ROW_BCAST15, bv);   // lane 31 = 0..31, lane 63 = 32..63
    DPP_MAXF(DPP_ROW_BCAST31, bv);   // lane 63 = full wave
    const int par = s & 1;
    if (lane == 63) swv[par*16 + wid] = bv;
    __syncthreads();
    // cross-wave value max: each lane reads slot (lane&15), 4 row stages.
    float sv = swv[par*16 + (lane & 15)];
    DPP_MAXF(DPP_ROW_SHR1, sv);
    DPP_MAXF(DPP_ROW_SHR2, sv);
    DPP_MAXF(DPP_ROW_SHR4, sv);
    DPP_MAXF(DPP_ROW_SHR8, sv);
    float bm = __int_as_float(
        __builtin_amdgcn_readlane(__float_as_int(sv), 15));  // block max
    // locate smallest local j with dist[j]==bm (descending cndmask chain)
    int bj = 16;
#pragma unroll
    for (int j = 15; j >= 0; --j){
      if (dist[j] == bm) bj = j;
    }
    unsigned long long mk = __ballot(bj < 16);
    int bi = t*16 + bj;                        // global index candidate
    int l0 = mk ? __builtin_ctzll(mk) : 0;     // lowest lane = smallest idx
    int wc = __builtin_amdgcn_readlane(bi, l0);
    if (mk == 0ull) wc = 0x7fffffff;
    if (lane == 0) swi[par*16 + wid] = wc;
    __syncthreads();
    // lowest valid slot = smallest global index among waves
    int iv = swi[par*16 + (lane & 15)];
    unsigned long long mk2 = __ballot(iv != 0x7fffffff);
    int l1 = __builtin_ctzll(mk2);             // nonzero: block max exists
    int ufi = __builtin_amdgcn_readlane(iv, l1);
    cx = sx[ufi];                              // LDS broadcast (uniform)
    cy = pb[ufi*3+1];                          // uniform, L2-hot
    cz = pb[ufi*3+2];
  }
}

// ---------------------------------------------------------------------------
// Ball query: one wave per center. Ordered compaction of the first 32
// in-radius indices (ascending index order == jnp.sort-then-truncate).
// ---------------------------------------------------------------------------
__global__ __launch_bounds__(256) void ballq_kernel(const float* __restrict__ pos,
                                                    const float* __restrict__ centers,
                                                    int* __restrict__ idx){
#pragma clang fp contract(off)
  const float R2 = (float)(0.2*0.2);   // match Python double 0.2*0.2 -> f32
  int wid  = blockIdx.x*4 + (threadIdx.x >> 6);
  int lane = threadIdx.x & 63;
  int b = wid >> 10;                   // wid / S
  const float* pb = pos + (size_t)b * NPTS * 3;
  float cx = centers[wid*3+0], cy = centers[wid*3+1], cz = centers[wid*3+2];
  int* out = idx + wid*KNEI;
  int count = 0; int first = -1;
  for (int base = 0; base < NPTS; base += 64){
    int p = base + lane;
    float dx = pb[p*3+0]-cx, dy = pb[p*3+1]-cy, dz = pb[p*3+2]-cz;
    float t1 = dx*dx, t2 = dy*dy, t3 = dz*dz;
    float d = (t1 + t2) + t3;
    bool inr = d <= R2;
    unsigned long long mask = __ballot(inr);
    if (count == 0 && mask) first = base + __builtin_ctzll(mask);
    if (inr){
      int slot = count + __popcll(mask & ((1ull << lane) - 1ull));
      if (slot < KNEI) out[slot] = p;
    }
    count += __popcll(mask);
    if (count >= KNEI) break;
  }
  if (count < KNEI){
    for (int slot = count + lane; slot < KNEI; slot += 64) out[slot] = first;
  }
}

// ---------------------------------------------------------------------------
// GEMM1 sem: h1[m][0:64] = feat[b, idx[m], :] @ w(64x64) + bias.
// Block: 256 threads, 64-row tile. Also accumulates per-channel sum/sumsq.
// ---------------------------------------------------------------------------
__global__ __launch_bounds__(256) void gemm_sem1(const float* __restrict__ feat,
    const int* __restrict__ idx, const float* __restrict__ w,
    const float* __restrict__ bias, float* __restrict__ h1,
    float* __restrict__ stat){
  __shared__ float xs[64][68];
  __shared__ float wsh[64][64];
  const int tid = threadIdx.x;
  const int m0 = blockIdx.x * 64;
#pragma unroll
  for (int i = 0; i < 4; ++i){
    int q = tid + i*256;                 // 1024 quads of w (64x64)
    int r = q >> 4, c4 = q & 15;
    *(float4*)&wsh[r][c4*4] = *(const float4*)&w[r*64 + c4*4];
  }
#pragma unroll
  for (int i = 0; i < 4; ++i){
    int q = tid + i*256;                 // 1024 quads of x tile (64x64)
    int r = q >> 4, c4 = q & 15;
    int m = m0 + r;
    int nb = idx[m];
    int b = m >> 15;                     // m / (S*KNEI)
    const float* fr = feat + ((size_t)b*NPTS + nb)*64;
    *(float4*)&xs[r][c4*4] = *(const float4*)&fr[c4*4];
  }
  __syncthreads();
  const int g  = tid & 7;                // channel group: 8 channels
  const int rt = tid >> 3;               // 32 row-threads, 2 rows each
  const int r0 = rt * 2;
  float acc[2][8];
#pragma unroll
  for (int c = 0; c < 8; ++c){ float bb = bias[g*8+c]; acc[0][c] = bb; acc[1][c] = bb; }
  for (int k = 0; k < 64; ++k){
    float x0 = xs[r0][k], x1 = xs[r0+1][k];
    float4 wa = *(float4*)&wsh[k][g*8];
    float4 wb = *(float4*)&wsh[k][g*8+4];
    float wv[8] = {wa.x,wa.y,wa.z,wa.w,wb.x,wb.y,wb.z,wb.w};
#pragma unroll
    for (int c = 0; c < 8; ++c){ acc[0][c] += x0*wv[c]; acc[1][c] += x1*wv[c]; }
  }
#pragma unroll
  for (int r = 0; r < 2; ++r){
    float* dst = h1 + (size_t)(m0 + r0 + r)*64 + g*8;
    *(float4*)dst     = make_float4(acc[r][0],acc[r][1],acc[r][2],acc[r][3]);
    *(float4*)(dst+4) = make_float4(acc[r][4],acc[r][5],acc[r][6],acc[r][7]);
  }
  float ls[8], lq[8];
#pragma unroll
  for (int c = 0; c < 8; ++c){
    ls[c] = acc[0][c] + acc[1][c];
    lq[c] = acc[0][c]*acc[0][c] + acc[1][c]*acc[1][c];
  }
  __syncthreads();
  float* red  = &xs[0][0];
  float* redq = &wsh[0][0];
#pragma unroll
  for (int c = 0; c < 8; ++c){
    red[(g*8+c)*32 + rt]  = ls[c];
    redq[(g*8+c)*32 + rt] = lq[c];
  }
  __syncthreads();
  if (tid < 128){
    int c = tid & 63;
    const float* src = (tid < 64) ? red : redq;
    float a2 = 0.f;
    for (int i = 0; i < 32; ++i) a2 += src[c*32+i];
    atomicAdd(&stat[(tid < 64 ? 0 : 64) + c], a2);
  }
}

// ---------------------------------------------------------------------------
// GEMM2 (sem & geo layer 2): x = relu(a*hin+d) (folded BN1), out 128 ch.
// ---------------------------------------------------------------------------
__global__ __launch_bounds__(256) void gemm2_kernel(const float* __restrict__ hin,
    const float* __restrict__ abn, const float* __restrict__ dbn,
    const float* __restrict__ w, const float* __restrict__ bias,
    float* __restrict__ hout, float* __restrict__ stat){
  __shared__ float xs[64][68];
  __shared__ float wsh[64][128];
  const int tid = threadIdx.x;
  const int m0 = blockIdx.x * 64;
#pragma unroll
  for (int i = 0; i < 8; ++i){
    int q = tid + i*256;                 // 2048 quads of w (64x128)
    int r = q >> 5, c4 = q & 31;
    *(float4*)&wsh[r][c4*4] = *(const float4*)&w[r*128 + c4*4];
  }
#pragma unroll
  for (int i = 0; i < 4; ++i){
    int q = tid + i*256;
    int r = q >> 4, c4 = q & 15;
    float4 v  = *(const float4*)&hin[(size_t)(m0+r)*64 + c4*4];
    float4 av = *(const float4*)&abn[c4*4];
    float4 dv = *(const float4*)&dbn[c4*4];
    v.x = fmaxf(v.x*av.x + dv.x, 0.f);
    v.y = fmaxf(v.y*av.y + dv.y, 0.f);
    v.z = fmaxf(v.z*av.z + dv.z, 0.f);
    v.w = fmaxf(v.w*av.w + dv.w, 0.f);
    *(float4*)&xs[r][c4*4] = v;
  }
  __syncthreads();
  const int g  = tid & 15;               // 16 groups x 8 ch = 128
  const int rt = tid >> 4;               // 16 row-threads x 4 rows = 64
  const int r0 = rt * 4;
  float acc[4][8];
#pragma unroll
  for (int c = 0; c < 8; ++c){
    float bb = bias[g*8+c];
    acc[0][c]=bb; acc[1][c]=bb; acc[2][c]=bb; acc[3][c]=bb;
  }
  for (int k = 0; k < 64; ++k){
    float x0 = xs[r0][k], x1 = xs[r0+1][k], x2 = xs[r0+2][k], x3 = xs[r0+3][k];
    float4 wa = *(float4*)&wsh[k][g*8];
    float4 wb = *(float4*)&wsh[k][g*8+4];
    float wv[8] = {wa.x,wa.y,wa.z,wa.w,wb.x,wb.y,wb.z,wb.w};
#pragma unroll
    for (int c = 0; c < 8; ++c){
      acc[0][c] += x0*wv[c]; acc[1][c] += x1*wv[c];
      acc[2][c] += x2*wv[c]; acc[3][c] += x3*wv[c];
    }
  }
#pragma unroll
  for (int r = 0; r < 4; ++r){
    float* dst = hout + (size_t)(m0 + r0 + r)*128 + g*8;
    *(float4*)dst     = make_float4(acc[r][0],acc[r][1],acc[r][2],acc[r][3]);
    *(float4*)(dst+4) = make_float4(acc[r][4],acc[r][5],acc[r][6],acc[r][7]);
  }
  float ls[8], lq[8];
#pragma unroll
  for (int c = 0; c < 8; ++c){
    ls[c] = acc[0][c]+acc[1][c]+acc[2][c]+acc[3][c];
    lq[c] = acc[0][c]*acc[0][c]+acc[1][c]*acc[1][c]+acc[2][c]*acc[2][c]+acc[3][c]*acc[3][c];
  }
  __syncthreads();
  float* red = &xs[0][0];                // 2048 sums + 2048 sumsq (fits 64*68)
#pragma unroll
  for (int c = 0; c < 8; ++c){
    red[(g*8+c)*16 + rt]        = ls[c];
    red[2048 + (g*8+c)*16 + rt] = lq[c];
  }
  __syncthreads();
  {
    int c = tid & 127;
    int isq = tid >> 7;
    float a2 = 0.f;
    for (int i = 0; i < 16; ++i) a2 += red[isq*2048 + c*16 + i];
    atomicAdd(&stat[isq*128 + c], a2);
  }
}

// ---------------------------------------------------------------------------
// GEMM1 geo: x = [center(3) | grouped_pos(3)] (6 ch) @ w(6x64) + bias.
// ---------------------------------------------------------------------------
__global__ __launch_bounds__(256) void gemm_geo1(const float* __restrict__ pos,
    const float* __restrict__ centers, const int* __restrict__ idx,
    const float* __restrict__ w, const float* __restrict__ bias,
    float* __restrict__ hout, float* __restrict__ stat){
  __shared__ float xs[64][8];
  __shared__ float wsh[6][64];
  __shared__ float red[2048];
  __shared__ float redq[2048];
  const int tid = threadIdx.x;
  const int m0 = blockIdx.x * 64;
  for (int i = tid; i < 384; i += 256) wsh[i >> 6][i & 63] = w[i];
  if (tid < 64){
    int m = m0 + tid;
    int grp = m >> 5;                    // m / KNEI
    int b = m >> 15;
    int nb = idx[m];
    const float* cp = centers + (size_t)grp*3;
    const float* pp = pos + ((size_t)b*NPTS + nb)*3;
    xs[tid][0]=cp[0]; xs[tid][1]=cp[1]; xs[tid][2]=cp[2];
    xs[tid][3]=pp[0]; xs[tid][4]=pp[1]; xs[tid][5]=pp[2];
  }
  __syncthreads();
  const int g  = tid & 7;
  const int rt = tid >> 3;
  const int r0 = rt * 2;
  float acc[2][8];
#pragma unroll
  for (int c = 0; c < 8; ++c){ float bb = bias[g*8+c]; acc[0][c]=bb; acc[1][c]=bb; }
#pragma unroll
  for (int k = 0; k < 6; ++k){
    float x0 = xs[r0][k], x1 = xs[r0+1][k];
    float4 wa = *(float4*)&wsh[k][g*8];
    float4 wb = *(float4*)&wsh[k][g*8+4];
    float wv[8] = {wa.x,wa.y,wa.z,wa.w,wb.x,wb.y,wb.z,wb.w};
#pragma unroll
    for (int c = 0; c < 8; ++c){ acc[0][c] += x0*wv[c]; acc[1][c] += x1*wv[c]; }
  }
#pragma unroll
  for (int r = 0; r < 2; ++r){
    float* dst = hout + (size_t)(m0 + r0 + r)*64 + g*8;
    *(float4*)dst     = make_float4(acc[r][0],acc[r][1],acc[r][2],acc[r][3]);
    *(float4*)(dst+4) = make_float4(acc[r][4],acc[r][5],acc[r][6],acc[r][7]);
  }
  float ls[8], lq[8];
#pragma unroll
  for (int c = 0; c < 8; ++c){
    ls[c] = acc[0][c] + acc[1][c];
    lq[c] = acc[0][c]*acc[0][c] + acc[1][c]*acc[1][c];
  }
#pragma unroll
  for (int c = 0; c < 8; ++c){
    red[(g*8+c)*32 + rt]  = ls[c];
    redq[(g*8+c)*32 + rt] = lq[c];
  }
  __syncthreads();
  if (tid < 128){
    int c = tid & 63;
    const float* src = (tid < 64) ? red : redq;
    float a2 = 0.f;
    for (int i = 0; i < 32; ++i) a2 += src[c*32+i];
    atomicAdd(&stat[(tid < 64 ? 0 : 64) + c], a2);
  }
}

// ---------------------------------------------------------------------------
// BN finalize: fold stats into per-channel scale/shift a,d.
// ---------------------------------------------------------------------------
__global__ void bn_finalize(const float* __restrict__ stat,
                            const float* __restrict__ gam, const float* __restrict__ bet,
                            float* __restrict__ a, float* __restrict__ d, int C){
  int c = threadIdx.x;
  if (c >= C) return;
  const float invM = 1.0f / (float)MROWS;
  float mu  = stat[c] * invM;
  float ex2 = stat[C + c] * invM;
  float var = ex2 - mu*mu;
  float aa = gam[c] * rsqrtf(var + 1e-5f);
  a[c] = aa;
  d[c] = bet[c] - mu*aa;
}

// ---------------------------------------------------------------------------
// Max over K with folded BN2 + ReLU: out[grp][c] = relu(max_k (a*h+d)).
// ---------------------------------------------------------------------------
__global__ __launch_bounds__(256) void maxpool_kernel(const float* __restrict__ hin,
    const float* __restrict__ abn, const float* __restrict__ dbn,
    float* __restrict__ out){
  const int tid = threadIdx.x;
  const int grp = blockIdx.x*8 + (tid >> 5);
  const int c4 = tid & 31;
  const float* base = hin + (size_t)grp*KNEI*128 + c4*4;
  float4 a = *(const float4*)&abn[c4*4];
  float4 d = *(const float4*)&dbn[c4*4];
  float4 m = make_float4(-3.4e38f,-3.4e38f,-3.4e38f,-3.4e38f);
  for (int k = 0; k < KNEI; ++k){
    float4 v = *(const float4*)&base[(size_t)k*128];
    m.x = fmaxf(m.x, v.x*a.x + d.x);
    m.y = fmaxf(m.y, v.y*a.y + d.y);
    m.z = fmaxf(m.z, v.z*a.z + d.z);
    m.w = fmaxf(m.w, v.w*a.w + d.w);
  }
  m.x = fmaxf(m.x, 0.f); m.y = fmaxf(m.y, 0.f);
  m.z = fmaxf(m.z, 0.f); m.w = fmaxf(m.w, 0.f);
  *(float4*)&out[(size_t)grp*128 + c4*4] = m;
}

__global__ void zero_kernel(float* __restrict__ p, int n){
  int i = blockIdx.x*blockDim.x + threadIdx.x;
  if (i < n) p[i] = 0.f;
}

extern "C" void kernel_launch(void* const* d_in, const int* in_sizes, int n_in,
                              void* d_out, int out_size, void* d_ws, size_t ws_size,
                              hipStream_t stream){
  const float* pos   = (const float*)d_in[0];
  const float* feat  = (const float*)d_in[1];
  const float* w_s1  = (const float*)d_in[2];
  const float* b_s1  = (const float*)d_in[3];
  const float* g_s1  = (const float*)d_in[4];
  const float* be_s1 = (const float*)d_in[5];
  const float* w_s2  = (const float*)d_in[6];
  const float* b_s2  = (const float*)d_in[7];
  const float* g_s2  = (const float*)d_in[8];
  const float* be_s2 = (const float*)d_in[9];
  const float* w_g1  = (const float*)d_in[10];
  const float* b_g1  = (const float*)d_in[11];
  const float* g_g1  = (const float*)d_in[12];
  const float* be_g1 = (const float*)d_in[13];
  const float* w_g2  = (const float*)d_in[14];
  const float* b_g2  = (const float*)d_in[15];
  const float* g_g2  = (const float*)d_in[16];
  const float* be_g2 = (const float*)d_in[17];
  float* outp = (float*)d_out;
  float* wsf  = (float*)d_ws;

  // workspace layout (floats):
  float* centers = wsf;                         // 8192*3 = 24576
  int*   idxp    = (int*)(wsf + 24576);         // 262144
  float* stats   = wsf + 24576 + 262144;        // 768
  float* bnad    = stats + 768;                 // 768
  float* h1      = wsf + 288256;                // 262144*64
  float* h2      = h1 + (size_t)MROWS*64;       // 262144*128
  // total = 50,619,904 floats = ~193.1 MiB

  float* st1 = stats;        // 64 sum + 64 sq
  float* st2 = stats + 128;  // 128 + 128
  float* st3 = stats + 384;  // 64 + 64
  float* st4 = stats + 512;  // 128 + 128
  float* a1 = bnad;        float* d1 = bnad + 64;
  float* a2 = bnad + 128;  float* d2 = bnad + 256;
  float* a3 = bnad + 384;  float* d3 = bnad + 448;
  float* a4 = bnad + 512;  float* d4 = bnad + 640;

  // allow >64 KiB dynamic LDS for fps_kernel (idempotent)
  hipFuncSetAttribute((const void*)fps_kernel,
                      hipFuncAttributeMaxDynamicSharedMemorySize,
                      FPS_LDS_BYTES);

  zero_kernel<<<3, 256, 0, stream>>>(stats, 768);
  fps_kernel<<<NB, 1024, FPS_LDS_BYTES, stream>>>(pos, centers);
  ballq_kernel<<<(NB*S)/4, 256, 0, stream>>>(pos, centers, idxp);

  // sem branch
  gemm_sem1<<<MROWS/64, 256, 0, stream>>>(feat, idxp, w_s1, b_s1, h1, st1);
  bn_finalize<<<1, 128, 0, stream>>>(st1, g_s1, be_s1, a1, d1, 64);
  gemm2_kernel<<<MROWS/64, 256, 0, stream>>>(h1, a1, d1, w_s2, b_s2, h2, st2);
  bn_finalize<<<1, 128, 0, stream>>>(st2, g_s2, be_s2, a2, d2, 128);
  maxpool_kernel<<<(NB*S)/8, 256, 0, stream>>>(h2, a2, d2, outp);

  // geo branch (reuses h1/h2)
  gemm_geo1<<<MROWS/64, 256, 0, stream>>>(pos, centers, idxp, w_g1, b_g1, h1, st3);
  bn_finalize<<<1, 128, 0, stream>>>(st3, g_g1, be_g1, a3, d3, 64);
  gemm2_kernel<<<MROWS/64, 256, 0, stream>>>(h1, a3, d3, w_g2, b_g2, h2, st4);
  bn_finalize<<<1, 128, 0, stream>>>(st4, g_g2, be_g2, a4, d4, 128);
  maxpool_kernel<<<(NB*S)/8, 256, 0, stream>>>(h2, a4, d4, outp + (size_t)NB*S*128);
}